// Round 2
// baseline (520.506 us; speedup 1.0000x reference)
//
#include <hip/hip_runtime.h>
#include <hip/hip_bf16.h>

typedef __attribute__((ext_vector_type(8))) short short8;
typedef __attribute__((ext_vector_type(4))) short short4_t;
typedef __attribute__((ext_vector_type(4))) float float4_t;

#define S_LEN 2048
#define D_DIM 128
#define BQ 128
#define BK 64
#define KS_STRIDE 136   // K tile row stride (bf16 elems): 272 B, 16B-aligned, 2-way-free frag reads
#define VT_STRIDE 72    // V^T row stride: 144 B, 16B-aligned, rotates 4 banks/row
#define PS_STRIDE 72    // P tile row stride (per-wave region)

// RNE float->bf16 (inputs are finite randn; no NaN handling needed)
__device__ __forceinline__ short f2bf(float f) {
    union { float f; unsigned u; } x; x.f = f;
    unsigned r = x.u + 0x7fffu + ((x.u >> 16) & 1u);
    return (short)(r >> 16);
}

// hardware exp2 (v_exp_f32)
__device__ __forceinline__ float fast_exp2(float x) {
#if __has_builtin(__builtin_amdgcn_exp2f)
    return __builtin_amdgcn_exp2f(x);
#else
    return exp2f(x);
#endif
}

__global__ void __launch_bounds__(256, 2)
attn_fwd(const float* __restrict__ Q, const float* __restrict__ K,
         const float* __restrict__ V, float* __restrict__ Out)
{
    __shared__ __align__(16) short lds_k[BK * KS_STRIDE];        // 17408 B
    __shared__ __align__(16) short lds_vt[D_DIM * VT_STRIDE];    // 18432 B
    __shared__ __align__(16) short lds_p[4 * 32 * PS_STRIDE];    // 18432 B

    const int qtile = blockIdx.x;       // 0..15
    const int bh    = blockIdx.y;       // 0..63
    const long base = (long)bh * S_LEN * D_DIM;
    const int t    = threadIdx.x;
    const int wave = t >> 6;
    const int lane = t & 63;
    const int ln   = lane & 15;
    const int quad = lane >> 4;

    // logits in log2 domain: scale = log2(e)/sqrt(D)
    const float qscale = 1.4426950408889634f / 11.313708498984761f;

    // ---- load Q fragments (bf16, pre-scaled), held in registers all loop ----
    const int qrow0 = qtile * BQ + wave * 32;
    short8 qf[2][4];
    for (int rc = 0; rc < 2; ++rc)
        for (int ks = 0; ks < 4; ++ks) {
            const float* p = Q + base + (long)(qrow0 + 16 * rc + ln) * D_DIM + 32 * ks + 8 * quad;
            float4_t a = *(const float4_t*)p;
            float4_t b = *(const float4_t*)(p + 4);
            short8 f;
            f[0] = f2bf(a[0] * qscale); f[1] = f2bf(a[1] * qscale);
            f[2] = f2bf(a[2] * qscale); f[3] = f2bf(a[3] * qscale);
            f[4] = f2bf(b[0] * qscale); f[5] = f2bf(b[1] * qscale);
            f[6] = f2bf(b[2] * qscale); f[7] = f2bf(b[3] * qscale);
            qf[rc][ks] = f;
        }

    // ---- accumulators / online-softmax state ----
    float4_t o[2][8];
    for (int rc = 0; rc < 2; ++rc)
        for (int nc = 0; nc < 8; ++nc) { o[rc][nc][0]=0.f; o[rc][nc][1]=0.f; o[rc][nc][2]=0.f; o[rc][nc][3]=0.f; }
    float mrow[2][4], lrow[2][4];
    for (int rc = 0; rc < 2; ++rc)
        for (int r = 0; r < 4; ++r) { mrow[rc][r] = -__builtin_inff(); lrow[rc][r] = 0.f; }

    const int pbase = wave * 32 * PS_STRIDE;

    for (int kv0 = 0; kv0 < S_LEN; kv0 += BK) {
        __syncthreads();   // previous iter's frag reads done before restaging

        // ---- stage K tile: [BK][D] fp32 -> bf16 row-major ----
        {
            const int d0 = (t & 31) << 2;
            const int sr = t >> 5;
            for (int r = 0; r < 8; ++r) {
                const int s = sr + 8 * r;
                float4_t v = *(const float4_t*)(K + base + (long)(kv0 + s) * D_DIM + d0);
                short4_t w4;
                w4[0] = f2bf(v[0]); w4[1] = f2bf(v[1]); w4[2] = f2bf(v[2]); w4[3] = f2bf(v[3]);
                *(short4_t*)&lds_k[s * KS_STRIDE + d0] = w4;
            }
        }
        // ---- stage V tile transposed: Vt[d][s] (contiguous-in-lane b16 writes) ----
        {
            const int s = t & 63;
            const int dbase = (t >> 6) * 32;
            for (int r = 0; r < 8; ++r) {
                const int d0 = dbase + 4 * r;
                float4_t v = *(const float4_t*)(V + base + (long)(kv0 + s) * D_DIM + d0);
                lds_vt[(d0 + 0) * VT_STRIDE + s] = f2bf(v[0]);
                lds_vt[(d0 + 1) * VT_STRIDE + s] = f2bf(v[1]);
                lds_vt[(d0 + 2) * VT_STRIDE + s] = f2bf(v[2]);
                lds_vt[(d0 + 3) * VT_STRIDE + s] = f2bf(v[3]);
            }
        }
        __syncthreads();

        // ---- S = Q K^T  (32 MFMA/wave) ----
        float4_t sacc[2][4];
        for (int rc = 0; rc < 2; ++rc)
            for (int nc = 0; nc < 4; ++nc) { sacc[rc][nc][0]=0.f; sacc[rc][nc][1]=0.f; sacc[rc][nc][2]=0.f; sacc[rc][nc][3]=0.f; }
        for (int ks = 0; ks < 4; ++ks)
            for (int nc = 0; nc < 4; ++nc) {
                short8 bk_ = *(const short8*)&lds_k[(16 * nc + ln) * KS_STRIDE + 32 * ks + 8 * quad];
                sacc[0][nc] = __builtin_amdgcn_mfma_f32_16x16x32_bf16(qf[0][ks], bk_, sacc[0][nc], 0, 0, 0);
                sacc[1][nc] = __builtin_amdgcn_mfma_f32_16x16x32_bf16(qf[1][ks], bk_, sacc[1][nc], 0, 0, 0);
            }

        // ---- online softmax (rows = 16rc + 4quad + r; cols across ln & nc) ----
        float alpha[2][4], mnew[2][4];
        for (int rc = 0; rc < 2; ++rc)
            for (int r = 0; r < 4; ++r) {
                float mx = fmaxf(fmaxf(sacc[rc][0][r], sacc[rc][1][r]),
                                 fmaxf(sacc[rc][2][r], sacc[rc][3][r]));
                mx = fmaxf(mx, __shfl_xor(mx, 1));
                mx = fmaxf(mx, __shfl_xor(mx, 2));
                mx = fmaxf(mx, __shfl_xor(mx, 4));
                mx = fmaxf(mx, __shfl_xor(mx, 8));
                const float mn = fmaxf(mrow[rc][r], mx);
                alpha[rc][r] = fast_exp2(mrow[rc][r] - mn);
                mrow[rc][r] = mn;
                mnew[rc][r] = mn;
            }

        for (int rc = 0; rc < 2; ++rc) {
            float rs0 = 0.f, rs1 = 0.f, rs2 = 0.f, rs3 = 0.f;
            for (int nc = 0; nc < 4; ++nc) {
                const int cb = pbase + 16 * nc + ln;
                float p0 = fast_exp2(sacc[rc][nc][0] - mnew[rc][0]);
                float p1 = fast_exp2(sacc[rc][nc][1] - mnew[rc][1]);
                float p2 = fast_exp2(sacc[rc][nc][2] - mnew[rc][2]);
                float p3 = fast_exp2(sacc[rc][nc][3] - mnew[rc][3]);
                rs0 += p0; rs1 += p1; rs2 += p2; rs3 += p3;
                const int rbase = 16 * rc + 4 * quad;
                lds_p[cb + (rbase + 0) * PS_STRIDE] = f2bf(p0);
                lds_p[cb + (rbase + 1) * PS_STRIDE] = f2bf(p1);
                lds_p[cb + (rbase + 2) * PS_STRIDE] = f2bf(p2);
                lds_p[cb + (rbase + 3) * PS_STRIDE] = f2bf(p3);
            }
            float rs[4] = { rs0, rs1, rs2, rs3 };
            for (int r = 0; r < 4; ++r) {
                float s = rs[r];
                s += __shfl_xor(s, 1);
                s += __shfl_xor(s, 2);
                s += __shfl_xor(s, 4);
                s += __shfl_xor(s, 8);
                lrow[rc][r] = lrow[rc][r] * alpha[rc][r] + s;
            }
        }

        // rescale O accumulator by alpha (per-row, reg index == row within quad)
        for (int rc = 0; rc < 2; ++rc)
            for (int nc = 0; nc < 8; ++nc) {
                o[rc][nc][0] *= alpha[rc][0];
                o[rc][nc][1] *= alpha[rc][1];
                o[rc][nc][2] *= alpha[rc][2];
                o[rc][nc][3] *= alpha[rc][3];
            }

        // wave-private P write -> read: drain LDS queue (same-CU visibility)
        __asm__ volatile("s_waitcnt lgkmcnt(0)" ::: "memory");

        // ---- O += P V  (32 MFMA/wave) ----
        for (int ks = 0; ks < 2; ++ks) {
            short8 ap0 = *(const short8*)&lds_p[pbase + (ln)      * PS_STRIDE + 32 * ks + 8 * quad];
            short8 ap1 = *(const short8*)&lds_p[pbase + (16 + ln) * PS_STRIDE + 32 * ks + 8 * quad];
            for (int nc = 0; nc < 8; ++nc) {
                short8 bv = *(const short8*)&lds_vt[(16 * nc + ln) * VT_STRIDE + 32 * ks + 8 * quad];
                o[0][nc] = __builtin_amdgcn_mfma_f32_16x16x32_bf16(ap0, bv, o[0][nc], 0, 0, 0);
                o[1][nc] = __builtin_amdgcn_mfma_f32_16x16x32_bf16(ap1, bv, o[1][nc], 0, 0, 0);
            }
        }
    }

    // ---- epilogue: O / l ----
    for (int rc = 0; rc < 2; ++rc)
        for (int r = 0; r < 4; ++r) {
            const float inv = 1.0f / lrow[rc][r];
            const int row = qrow0 + 16 * rc + 4 * quad + r;
            float* po = Out + base + (long)row * D_DIM;
            for (int nc = 0; nc < 8; ++nc)
                po[16 * nc + ln] = o[rc][nc][r] * inv;
        }
}

extern "C" void kernel_launch(void* const* d_in, const int* in_sizes, int n_in,
                              void* d_out, int out_size, void* d_ws, size_t ws_size,
                              hipStream_t stream) {
    (void)in_sizes; (void)n_in; (void)d_ws; (void)ws_size; (void)out_size;
    const float* Q = (const float*)d_in[0];
    const float* K = (const float*)d_in[1];
    const float* V = (const float*)d_in[2];
    float* Out = (float*)d_out;
    dim3 grid(S_LEN / BQ, 64, 1);   // x = q-tile (fast-varying -> same-bh blocks co-resident)
    dim3 block(256, 1, 1);
    attn_fwd<<<grid, block, 0, stream>>>(Q, K, V, Out);
}